// Round 4
// baseline (419.428 us; speedup 1.0000x reference)
//
#include <hip/hip_runtime.h>
#include <hip/hip_bf16.h>
#include <math.h>

#define N_Q 20000
#define KK 48
#define CC 64
#define FFD 256

// ws float offsets
#define TW_WOT   0        // 4096:  WoT[j*64+c]      = out_w[c*64+j]
#define TW_WVT   4096     // 4096:  WvT[cp*64+c]     = in_w[(128+c)*64+cp]  (Wv[c,cp])
#define TW_L1I   8192     // 16384: L1I[j*256+f]     = lin1_w[f*64+j]
#define TW_L2I   24576    // 16384: L2I[f4*256+4c+m] = lin2_w[c*256+4*f4+m]
#define TW_OLT   40960    // 4096:  OlT[j*64+o]      = outl_w[o*64+j]
#define ST_OFF   45056    // 256 floats: sum1,sumsq1,sum2,sumsq2
#define M_OFF    45568    // bf16 M_all[n][j*4+h], 20000*256 ushorts

// ---------------------------------------------------------------------------
__global__ void prep_weights(const float* __restrict__ in_w,
                             const float* __restrict__ out_w,
                             const float* __restrict__ lin1_w,
                             const float* __restrict__ lin2_w,
                             const float* __restrict__ outl_w,
                             float* __restrict__ tw)
{
    int t = blockIdx.x * 256 + threadIdx.x;
    if (t < 4096) {
        int c = t >> 6, j = t & 63;
        tw[TW_WOT + j*64 + c] = out_w[c*64 + j];
    } else if (t < 8192) {
        int i = t - 4096, cp = i >> 6, c = i & 63;
        tw[TW_WVT + cp*64 + c] = in_w[(128 + c)*64 + cp];
    } else if (t < 24576) {
        int i = t - 8192, f = i >> 6, j = i & 63;
        tw[TW_L1I + j*256 + f] = lin1_w[f*64 + j];
    } else if (t < 40960) {
        int i = t - 24576, c = i >> 8, fm = i & 255;
        tw[TW_L2I + (fm >> 2)*256 + 4*c + (fm & 3)] = lin2_w[c*256 + fm];
    } else if (t < 45056) {
        int i = t - 40960, o = i >> 6, j = i & 63;
        tw[TW_OLT + j*64 + o] = outl_w[o*64 + j];
    }
}

// ---------------------------------------------------------------------------
// M_all[n][j,h] = sum_d q[n,h*16+d] * Wk[h*16+d, j]; q = (Wq@relu(qw@qc+qb)+bq)/4
// Weights hoisted into VGPRs after one LDS staging pass; 32 queries/block.
// ---------------------------------------------------------------------------
__global__ __launch_bounds__(256, 1) void m_kernel(
    const float* __restrict__ qcoord, const float* __restrict__ q_w,
    const float* __restrict__ q_b, const float* __restrict__ in_w,
    const float* __restrict__ in_b, __hip_bfloat16* __restrict__ M_all)
{
    __shared__ float sWq[64*65];
    __shared__ float sWk[64*65];
    __shared__ float sqf[4][64];
    __shared__ float sq[4][64];
    int tid = threadIdx.x;
    for (int i = tid; i < 8192; i += 256) {
        int r = i >> 6, j = i & 63;
        float v = in_w[i];
        if (r < 64) sWq[r*65 + j] = v; else sWk[(r - 64)*65 + j] = v;
    }
    __syncthreads();
    int w = tid >> 6, c = tid & 63;
    int j_lo = c & 15, h = c >> 4;

    // hoist: Wq row c, and Wk columns {j_lo, j_lo+16, j_lo+32, j_lo+48} for head h
    float wqr[64];
    #pragma unroll
    for (int j = 0; j < 64; ++j) wqr[j] = sWq[c*65 + j];
    float wkm[16][4];
    #pragma unroll
    for (int d = 0; d < 16; ++d) {
        const float* wr = &sWk[(h*16 + d)*65];
        wkm[d][0] = wr[j_lo];      wkm[d][1] = wr[j_lo + 16];
        wkm[d][2] = wr[j_lo + 32]; wkm[d][3] = wr[j_lo + 48];
    }

    float qw0 = q_w[c*3+0], qw1 = q_w[c*3+1], qw2 = q_w[c*3+2];
    float qb = q_b[c], bq = in_b[c];
    for (int qi = 0; qi < 8; ++qi) {
        int n = blockIdx.x*32 + w*8 + qi;
        float qc0 = qcoord[n*3+0], qc1 = qcoord[n*3+1], qc2 = qcoord[n*3+2];
        float qf = fmaf(qw2, qc2, qb); qf = fmaf(qw1, qc1, qf); qf = fmaf(qw0, qc0, qf);
        sqf[w][c] = fmaxf(qf, 0.0f);           // single wave: in-order LDS
        float q = bq;
        #pragma unroll 8
        for (int j = 0; j < 64; ++j) q = fmaf(sqf[w][j], wqr[j], q);
        q *= 0.25f;
        sq[w][c] = q;
        float m0 = 0, m1 = 0, m2 = 0, m3 = 0;
        #pragma unroll
        for (int d = 0; d < 16; ++d) {
            float qv = sq[w][h*16 + d];
            m0 = fmaf(qv, wkm[d][0], m0);
            m1 = fmaf(qv, wkm[d][1], m1);
            m2 = fmaf(qv, wkm[d][2], m2);
            m3 = fmaf(qv, wkm[d][3], m3);
        }
        __hip_bfloat16* Mp = M_all + (size_t)n*256;
        Mp[ j_lo       *4 + h] = __float2bfloat16(m0);
        Mp[(j_lo + 16) *4 + h] = __float2bfloat16(m1);
        Mp[(j_lo + 32) *4 + h] = __float2bfloat16(m2);
        Mp[(j_lo + 48) *4 + h] = __float2bfloat16(m3);
    }
}

// ---------------------------------------------------------------------------
// One wave per query. Deep-pipelined gather: 12 independent dwordx4 loads
// (16 lanes per row, 4 rows per issue), pe folded into the single LDS write.
// Then S = KF@M, softmax, T = P@KF, ctx = T@WvT + bv, att = WoT'ctx + bo.
// Barrier-free (single wave, same-wave LDS ops are in program order).
// ---------------------------------------------------------------------------
__global__ __launch_bounds__(64, 2) void attn_kernel(
    const float* __restrict__ vfeat, const float* __restrict__ vcoord,
    const float* __restrict__ qcoord, const int* __restrict__ kidx,
    const float* __restrict__ kpos_w, const float* __restrict__ kpos_b,
    const float* __restrict__ in_b, const float* __restrict__ out_b,
    const float* __restrict__ tw, const __hip_bfloat16* __restrict__ M_all,
    float* __restrict__ att_out)
{
    __shared__ __align__(16) float skf[KK*68];   // pitch 68 floats: rows 16B-aligned, 2-way banks
    __shared__ __align__(16) float reg1[256];    // sM | sP[0..192) | sctx[192..256)
    __shared__ __align__(16) float sT[4*65];
    int n = blockIdx.x, c = threadIdx.x;
    int l16 = c & 15, h = c >> 4;

    float* sM   = reg1;         // 256 floats, dead after score loop
    float* sP   = reg1;         // 192 floats, written post-softmax
    float* sctx = reg1 + 192;   // 64 floats, written post-ctx

    // stage M (bf16 -> f32)
    {
        uint2 mu = ((const uint2*)(M_all + (size_t)n*256))[c];
        float4 mf;
        mf.x = __uint_as_float(mu.x << 16);
        mf.y = __uint_as_float(mu.x & 0xffff0000u);
        mf.z = __uint_as_float(mu.y << 16);
        mf.w = __uint_as_float(mu.y & 0xffff0000u);
        *(float4*)&sM[4*c] = mf;
    }

    float qc0 = qcoord[n*3+0], qc1 = qcoord[n*3+1], qc2 = qcoord[n*3+2];

    // lanes 0..47: key index + relative coords
    int kread = c < 48 ? c : 47;
    int idxv = kidx[(size_t)n*KK + kread];
    int sfe = idxv < 0 ? 0 : idxv;
    float rl0 = vcoord[sfe*3+0] - qc0;
    float rl1 = vcoord[sfe*3+1] - qc1;
    float rl2 = vcoord[sfe*3+2] - qc2;

    // kpos params for this lane's 4 columns (j = 4*l16 + 0..3)
    float4 wA  = *(const float4*)(kpos_w + 12*l16 + 0);
    float4 wB  = *(const float4*)(kpos_w + 12*l16 + 4);
    float4 wC  = *(const float4*)(kpos_w + 12*l16 + 8);
    float4 kb4 = *(const float4*)(kpos_b + 4*l16);

    // ---- issue all 12 gather loads (fully independent, 16B each) ----
    float4 fv[12];
    #pragma unroll
    for (int i = 0; i < 12; ++i) {
        int row = 4*i + h;
        int si = __shfl(idxv, row);
        si = si < 0 ? 0 : si;
        fv[i] = *(const float4*)(vfeat + (size_t)si*64 + 4*l16);
    }
    // ---- consume: add positional encoding, write KF rows ----
    #pragma unroll
    for (int i = 0; i < 12; ++i) {
        int row = 4*i + h;
        float rr0 = __shfl(rl0, row), rr1 = __shfl(rl1, row), rr2 = __shfl(rl2, row);
        float4 o = fv[i];
        o.x += fmaxf(fmaf(wA.x, rr0, fmaf(wA.y, rr1, fmaf(wA.z, rr2, kb4.x))), 0.0f);
        o.y += fmaxf(fmaf(wA.w, rr0, fmaf(wB.x, rr1, fmaf(wB.y, rr2, kb4.y))), 0.0f);
        o.z += fmaxf(fmaf(wB.z, rr0, fmaf(wB.w, rr1, fmaf(wC.x, rr2, kb4.z))), 0.0f);
        o.w += fmaxf(fmaf(wC.y, rr0, fmaf(wC.z, rr1, fmaf(wC.w, rr2, kb4.w))), 0.0f);
        *(float4*)&skf[row*68 + 4*l16] = o;
    }

    // ---- scores: lane (l16,h) computes S[h, l16], S[h, l16+16], S[h, l16+32]
    int i0 = __shfl(idxv, l16), i1 = __shfl(idxv, l16 + 16), i2 = __shfl(idxv, l16 + 32);
    float S0 = 0, S1 = 0, S2 = 0;
    #pragma unroll
    for (int j4 = 0; j4 < 16; ++j4) {
        float4 a = *(const float4*)&skf[ l16       *68 + 4*j4];
        float4 b = *(const float4*)&skf[(l16 + 16) *68 + 4*j4];
        float4 d = *(const float4*)&skf[(l16 + 32) *68 + 4*j4];
        float m0 = sM[(4*j4 + 0)*4 + h], m1 = sM[(4*j4 + 1)*4 + h];
        float m2 = sM[(4*j4 + 2)*4 + h], m3 = sM[(4*j4 + 3)*4 + h];
        S0 = fmaf(a.x, m0, S0); S0 = fmaf(a.y, m1, S0); S0 = fmaf(a.z, m2, S0); S0 = fmaf(a.w, m3, S0);
        S1 = fmaf(b.x, m0, S1); S1 = fmaf(b.y, m1, S1); S1 = fmaf(b.z, m2, S1); S1 = fmaf(b.w, m3, S1);
        S2 = fmaf(d.x, m0, S2); S2 = fmaf(d.y, m1, S2); S2 = fmaf(d.z, m2, S2); S2 = fmaf(d.w, m3, S2);
    }
    if (i0 < 0) S0 = -INFINITY;
    if (i1 < 0) S1 = -INFINITY;
    if (i2 < 0) S2 = -INFINITY;

    // ---- softmax across the 16 lanes of head h ----
    float mx = fmaxf(S0, fmaxf(S1, S2));
    #pragma unroll
    for (int off = 8; off >= 1; off >>= 1) mx = fmaxf(mx, __shfl_xor(mx, off, 16));
    float e0 = __expf(S0 - mx), e1 = __expf(S1 - mx), e2 = __expf(S2 - mx);
    float es = e0 + e1 + e2;
    #pragma unroll
    for (int off = 8; off >= 1; off >>= 1) es += __shfl_xor(es, off, 16);
    float rinv = 1.0f / es;
    sP[ l16       *4 + h] = e0 * rinv;
    sP[(l16 + 16) *4 + h] = e1 * rinv;
    sP[(l16 + 32) *4 + h] = e2 * rinv;

    // ---- T[h', c] = sum_k P[h',k] * KF[k,c] ----
    float T0 = 0, T1 = 0, T2 = 0, T3 = 0;
    #pragma unroll 8
    for (int k = 0; k < KK; ++k) {
        float kf = skf[k*68 + c];
        float4 p = *(const float4*)&sP[k*4];      // broadcast
        T0 = fmaf(p.x, kf, T0); T1 = fmaf(p.y, kf, T1);
        T2 = fmaf(p.z, kf, T2); T3 = fmaf(p.w, kf, T3);
    }
    sT[0*65 + c] = T0; sT[1*65 + c] = T1; sT[2*65 + c] = T2; sT[3*65 + c] = T3;

    // ---- ctx[c] = bv[c] + sum_cp T[h(c), cp] * Wv[c, cp] ----
    const float* WvT = tw + TW_WVT;
    float ctx = in_b[128 + c];
    #pragma unroll 8
    for (int cp = 0; cp < 64; ++cp)
        ctx = fmaf(sT[h*65 + cp], WvT[cp*64 + c], ctx);
    sctx[c] = ctx;

    // ---- att[c] = bo[c] + sum_j ctx[j] * Wo[c, j] ----
    const float* WoT = tw + TW_WOT;
    float att = out_b[c];
    #pragma unroll 8
    for (int j = 0; j < 64; ++j)
        att = fmaf(sctx[j], WoT[j*64 + c], att);
    att_out[(size_t)n*64 + c] = att;
}

// ---------------------------------------------------------------------------
// FFN in-place on d_out: y = att + lin2(relu(lin1(att))). Weights streamed
// from L2 once per 8 queries (register blocking). BN1 stats accumulated.
// ---------------------------------------------------------------------------
__global__ __launch_bounds__(256) void ffn_kernel(
    const float* __restrict__ tw, const float* __restrict__ lin1_b,
    const float* __restrict__ lin2_b, float* __restrict__ att_y,
    float* __restrict__ sum1, float* __restrict__ sumsq1)
{
    __shared__ __align__(16) float satt[4][8*64];
    __shared__ __align__(16) float shid[4][8*256];
    int tid = threadIdx.x, w = tid >> 6, c = tid & 63;
    const float* L1I = tw + TW_L1I;
    const float* L2I = tw + TW_L2I;
    int base = blockIdx.x*32 + w*8;

    #pragma unroll
    for (int q = 0; q < 8; ++q)
        satt[w][q*64 + c] = att_y[(size_t)(base + q)*64 + c];

    float4 lb1 = *(const float4*)&lin1_b[4*c];    // lane c owns hidden f=4c..4c+3
    float acc[8][4];
    #pragma unroll
    for (int q = 0; q < 8; ++q) {
        acc[q][0] = lb1.x; acc[q][1] = lb1.y; acc[q][2] = lb1.z; acc[q][3] = lb1.w;
    }
    for (int j = 0; j < 64; ++j) {
        float4 w4 = *(const float4*)&L1I[j*256 + 4*c];
        #pragma unroll
        for (int q = 0; q < 8; ++q) {
            float a = satt[w][q*64 + j];
            acc[q][0] = fmaf(a, w4.x, acc[q][0]);
            acc[q][1] = fmaf(a, w4.y, acc[q][1]);
            acc[q][2] = fmaf(a, w4.z, acc[q][2]);
            acc[q][3] = fmaf(a, w4.w, acc[q][3]);
        }
    }
    #pragma unroll
    for (int q = 0; q < 8; ++q) {
        float4 hv;
        hv.x = fmaxf(acc[q][0], 0.0f); hv.y = fmaxf(acc[q][1], 0.0f);
        hv.z = fmaxf(acc[q][2], 0.0f); hv.w = fmaxf(acc[q][3], 0.0f);
        *(float4*)&shid[w][q*256 + 4*c] = hv;
    }
    float lb2 = lin2_b[c];
    float y[8];
    #pragma unroll
    for (int q = 0; q < 8; ++q) y[q] = lb2 + satt[w][q*64 + c];   // residual
    for (int f4 = 0; f4 < 64; ++f4) {
        float4 w4 = *(const float4*)&L2I[f4*256 + 4*c];
        #pragma unroll
        for (int q = 0; q < 8; ++q) {
            float4 hv = *(const float4*)&shid[w][q*256 + 4*f4];   // broadcast
            y[q] = fmaf(w4.x, hv.x, y[q]); y[q] = fmaf(w4.y, hv.y, y[q]);
            y[q] = fmaf(w4.z, hv.z, y[q]); y[q] = fmaf(w4.w, hv.w, y[q]);
        }
    }
    float s = 0, ss = 0;
    #pragma unroll
    for (int q = 0; q < 8; ++q) {
        float yv = y[q];
        att_y[(size_t)(base + q)*64 + c] = yv;
        s += yv; ss = fmaf(yv, yv, ss);
    }
    atomicAdd(&sum1[c], s); atomicAdd(&sumsq1[c], ss);
}

// ---------------------------------------------------------------------------
// BN1 (inline stats) + output linear, in-place on d_out; BN2 stats.
// Ol column hoisted into 64 VGPRs; y-row prefetch; 16 rows/block.
// ---------------------------------------------------------------------------
__global__ __launch_bounds__(64) void linout_kernel(
    const float* __restrict__ tw, const float* __restrict__ outl_b,
    const float* __restrict__ norm_g, const float* __restrict__ norm_b,
    const float* __restrict__ sum1, const float* __restrict__ sumsq1,
    float* __restrict__ yz, float* __restrict__ sum2, float* __restrict__ sumsq2)
{
    __shared__ __align__(16) float sxn[64];
    int c = threadIdx.x;
    const float* OlT = tw + TW_OLT;
    float wcol[64];
    #pragma unroll
    for (int j = 0; j < 64; ++j) wcol[j] = OlT[j*64 + c];   // coalesced
    const float invN = 1.0f / 20000.0f;
    float mu = sum1[c]*invN;
    float var = fmaf(-mu, mu, sumsq1[c]*invN);
    float a1 = norm_g[c] / sqrtf(var + 1e-5f);
    float b1 = fmaf(-mu, a1, norm_b[c]);
    float ob = outl_b[c];
    float s = 0, ss = 0;
    int base = blockIdx.x*16;
    float ynext = yz[(size_t)base*64 + c];
    for (int r = 0; r < 16; ++r) {
        float yv = ynext;
        if (r < 15) ynext = yz[(size_t)(base + r + 1)*64 + c];
        sxn[c] = fmaf(yv, a1, b1);                 // single wave: in-order
        float z = ob;
        #pragma unroll 8
        for (int j = 0; j < 64; ++j) z = fmaf(sxn[j], wcol[j], z);
        yz[(size_t)(base + r)*64 + c] = z;
        s += z; ss = fmaf(z, z, ss);
    }
    atomicAdd(&sum2[c], s); atomicAdd(&sumsq2[c], ss);
}

// ---------------------------------------------------------------------------
// out = relu(bn2(z)) in place; a2/b2 computed inline from sums.
// ---------------------------------------------------------------------------
__global__ void final_kernel(float* __restrict__ z,
    const float* __restrict__ sum2, const float* __restrict__ sumsq2,
    const float* __restrict__ obn_g, const float* __restrict__ obn_b)
{
    int i = blockIdx.x*blockDim.x + threadIdx.x;
    if (i >= N_Q*64/4) return;
    int o4 = (i*4) & 63;
    float4 sm = *(const float4*)&sum2[o4];
    float4 sq = *(const float4*)&sumsq2[o4];
    float4 g  = *(const float4*)&obn_g[o4];
    float4 b  = *(const float4*)&obn_b[o4];
    const float invN = 1.0f / 20000.0f;
    float mux = sm.x*invN, muy = sm.y*invN, muz = sm.z*invN, muw = sm.w*invN;
    float ax = g.x / sqrtf(fmaf(-mux, mux, sq.x*invN) + 1e-5f);
    float ay = g.y / sqrtf(fmaf(-muy, muy, sq.y*invN) + 1e-5f);
    float az = g.z / sqrtf(fmaf(-muz, muz, sq.z*invN) + 1e-5f);
    float aw = g.w / sqrtf(fmaf(-muw, muw, sq.w*invN) + 1e-5f);
    float4 v = ((float4*)z)[i];
    v.x = fmaxf(fmaf(v.x - mux, ax, b.x), 0.0f);
    v.y = fmaxf(fmaf(v.y - muy, ay, b.y), 0.0f);
    v.z = fmaxf(fmaf(v.z - muz, az, b.z), 0.0f);
    v.w = fmaxf(fmaf(v.w - muw, aw, b.w), 0.0f);
    ((float4*)z)[i] = v;
}

extern "C" void kernel_launch(void* const* d_in, const int* in_sizes, int n_in,
                              void* d_out, int out_size, void* d_ws, size_t ws_size,
                              hipStream_t stream)
{
    const float* vfeat  = (const float*)d_in[0];
    const float* vcoord = (const float*)d_in[1];
    const float* qcoord = (const float*)d_in[2];
    const int*   kidx   = (const int*)d_in[3];
    const float* q_w    = (const float*)d_in[4];
    const float* q_b    = (const float*)d_in[5];
    const float* kpos_w = (const float*)d_in[6];
    const float* kpos_b = (const float*)d_in[7];
    const float* in_w   = (const float*)d_in[8];
    const float* in_b   = (const float*)d_in[9];
    const float* out_w  = (const float*)d_in[10];
    const float* out_b  = (const float*)d_in[11];
    const float* lin1_w = (const float*)d_in[12];
    const float* lin1_b = (const float*)d_in[13];
    const float* lin2_w = (const float*)d_in[14];
    const float* lin2_b = (const float*)d_in[15];
    const float* norm_g = (const float*)d_in[16];
    const float* norm_b = (const float*)d_in[17];
    const float* outl_w = (const float*)d_in[18];
    const float* outl_b = (const float*)d_in[19];
    const float* obn_g  = (const float*)d_in[20];
    const float* obn_b  = (const float*)d_in[21];

    float* ws = (float*)d_ws;
    float* tw = ws;
    float* stats = ws + ST_OFF;
    float* sum1 = stats, *sumsq1 = stats + 64, *sum2 = stats + 128, *sumsq2 = stats + 192;
    __hip_bfloat16* M_all = (__hip_bfloat16*)(ws + M_OFF);
    float* xd = (float*)d_out;    // att -> y -> z -> out, all in place

    hipMemsetAsync(stats, 0, 256*sizeof(float), stream);
    prep_weights<<<176, 256, 0, stream>>>(in_w, out_w, lin1_w, lin2_w, outl_w, tw);
    m_kernel<<<625, 256, 0, stream>>>(qcoord, q_w, q_b, in_w, in_b, M_all);
    attn_kernel<<<N_Q, 64, 0, stream>>>(vfeat, vcoord, qcoord, kidx, kpos_w, kpos_b,
                                        in_b, out_b, tw, M_all, xd);
    ffn_kernel<<<625, 256, 0, stream>>>(tw, lin1_b, lin2_b, xd, sum1, sumsq1);
    linout_kernel<<<1250, 64, 0, stream>>>(tw, outl_b, norm_g, norm_b, sum1, sumsq1,
                                           xd, sum2, sumsq2);
    final_kernel<<<1250, 256, 0, stream>>>(xd, sum2, sumsq2, obn_g, obn_b);
}

// Round 5
// 221.899 us; speedup vs baseline: 1.8902x; 1.8902x over previous
//
#include <hip/hip_runtime.h>
#include <math.h>

#define N_Q 20000
#define KK 48
#define CC 64
#define FFD 256

// ws float offsets
#define TW_WOT   0        // 4096 f32: WoT[j*64+c] = out_w[c*64+j]        (attn)
#define TW_WVT   4096     // 4096 f32: WvT[cp*64+c] = in_w[(128+c)*64+cp] (attn)
#define TW_L1B   8192     // 8192 u32: lin1 B-frags  [ks2][nb16][lane64][4]
#define TW_L2B   16384    // 8192 u32: lin2 B-frags  [ks8][nb4][lane64][4]
#define TW_OLB   24576    // 2048 u32: outl B-frags  [ks2][nb4][lane64][4]
#define TW_QB    26624    // 2048 u32: Wq   B-frags  [ks2][nb4][lane64][4]
#define TW_KB    28672    // 4096 u32: Wk   B-frags  [h4][nb4][lane64][4] (k>=16 zero)
#define ST_OFF   32768    // 256 f32: sum1,sumsq1,sum2,sumsq2
#define M_OFF    33024    // bf16 M_all[n][j*4+h], 20000*256 ushorts

typedef short bf16x8 __attribute__((ext_vector_type(8)));
typedef float f32x4  __attribute__((ext_vector_type(4)));

__device__ __forceinline__ unsigned f2bf(float f) {
    unsigned u = __float_as_uint(f);
    return (u + 0x7fffu + ((u >> 16) & 1u)) >> 16;          // RNE to bf16
}
__device__ __forceinline__ unsigned pk2(float a, float b) {
    return f2bf(a) | (f2bf(b) << 16);
}
__device__ __forceinline__ bf16x8 ldfrag(const unsigned short* p) {
    return *(const bf16x8*)p;
}

// ---------------------------------------------------------------------------
// prep: attn fp32 transposes + bf16 MFMA B-fragment packs. 32768 threads.
// B-frag layout: value = W[n, k] with n = nb*16+(lane&15), k = ks*32+(lane>>4)*8+2*j2(+1)
// ---------------------------------------------------------------------------
__global__ void prep_weights(const float* __restrict__ in_w,
                             const float* __restrict__ out_w,
                             const float* __restrict__ lin1_w,
                             const float* __restrict__ lin2_w,
                             const float* __restrict__ outl_w,
                             float* __restrict__ tw)
{
    int t = blockIdx.x * 256 + threadIdx.x;
    unsigned* twu = (unsigned*)tw;
    if (t < 4096) {
        int c = t >> 6, j = t & 63;
        tw[TW_WOT + j*64 + c] = out_w[c*64 + j];
    } else if (t < 8192) {
        int i = t - 4096, cp = i >> 6, c = i & 63;
        tw[TW_WVT + cp*64 + c] = in_w[(128 + c)*64 + cp];
    } else if (t < 16384) {                    // L1B: H = att @ lin1_w^T
        int p = t - 8192;
        int j2 = p & 3, lane = (p >> 2) & 63, nb = (p >> 8) & 15, ks = p >> 12;
        int n = nb*16 + (lane & 15), k = ks*32 + (lane >> 4)*8 + 2*j2;
        twu[TW_L1B + p] = pk2(lin1_w[n*64 + k], lin1_w[n*64 + k + 1]);
    } else if (t < 24576) {                    // L2B: Y = H @ lin2_w^T
        int p = t - 16384;
        int j2 = p & 3, lane = (p >> 2) & 63, nb = (p >> 8) & 3, ks = p >> 10;
        int n = nb*16 + (lane & 15), k = ks*32 + (lane >> 4)*8 + 2*j2;
        twu[TW_L2B + p] = pk2(lin2_w[n*256 + k], lin2_w[n*256 + k + 1]);
    } else if (t < 26624) {                    // OLB: z = xn @ outl_w^T
        int p = t - 24576;
        int j2 = p & 3, lane = (p >> 2) & 63, nb = (p >> 8) & 3, ks = p >> 10;
        int n = nb*16 + (lane & 15), k = ks*32 + (lane >> 4)*8 + 2*j2;
        twu[TW_OLB + p] = pk2(outl_w[n*64 + k], outl_w[n*64 + k + 1]);
    } else if (t < 28672) {                    // QB: q = qf @ Wq^T (Wq = in_w rows 0..63)
        int p = t - 26624;
        int j2 = p & 3, lane = (p >> 2) & 63, nb = (p >> 8) & 3, ks = p >> 10;
        int n = nb*16 + (lane & 15), k = ks*32 + (lane >> 4)*8 + 2*j2;
        twu[TW_QB + p] = pk2(in_w[n*64 + k], in_w[n*64 + k + 1]);
    } else if (t < 32768) {                    // KB: M = q @ Wk (per head, K=16 zero-padded)
        int p = t - 28672;
        int j2 = p & 3, lane = (p >> 2) & 63, nb = (p >> 8) & 3, h = p >> 10;
        int j = nb*16 + (lane & 15), k = (lane >> 4)*8 + 2*j2;
        unsigned u = 0;
        if (k < 16)
            u = pk2(in_w[(64 + h*16 + k)*64 + j], in_w[(64 + h*16 + k + 1)*64 + j]);
        twu[TW_KB + p] = u;
    }
}

// ---------------------------------------------------------------------------
// m_kernel (MFMA): 80 queries/block. qf=relu(qc@qw^T+qb) staged bf16 ->
// q GEMM (wave w owns cols w*16..+15) -> per-head M GEMM (head = wave).
// ---------------------------------------------------------------------------
__global__ __launch_bounds__(256) void m_kernel(
    const float* __restrict__ qcoord, const float* __restrict__ q_w,
    const float* __restrict__ q_b, const float* __restrict__ in_b,
    const float* __restrict__ tw, unsigned short* __restrict__ M_all)
{
    __shared__ __align__(16) unsigned short sQF[80*72];
    __shared__ __align__(16) unsigned short sQ[80*72];
    int t = threadIdx.x, base = blockIdx.x * 80;
    int colq = (t*4) & 63;
    float qwv[12];
    #pragma unroll
    for (int j = 0; j < 12; ++j) qwv[j] = q_w[colq*3 + j];
    float4 qb4 = *(const float4*)&q_b[colq];
    #pragma unroll
    for (int i = 0; i < 5; ++i) {
        int e = i*1024 + t*4, r = e >> 6, n = base + r;
        float c0 = qcoord[n*3], c1 = qcoord[n*3+1], c2 = qcoord[n*3+2];
        float f0 = fmaxf(fmaf(qwv[2],  c2, fmaf(qwv[1],  c1, fmaf(qwv[0], c0, qb4.x))), 0.f);
        float f1 = fmaxf(fmaf(qwv[5],  c2, fmaf(qwv[4],  c1, fmaf(qwv[3], c0, qb4.y))), 0.f);
        float f2 = fmaxf(fmaf(qwv[8],  c2, fmaf(qwv[7],  c1, fmaf(qwv[6], c0, qb4.z))), 0.f);
        float f3 = fmaxf(fmaf(qwv[11], c2, fmaf(qwv[10], c1, fmaf(qwv[9], c0, qb4.w))), 0.f);
        uint2 p; p.x = pk2(f0, f1); p.y = pk2(f2, f3);
        *(uint2*)&sQF[r*72 + colq] = p;
    }
    int w = t >> 6, lane = t & 63, l16 = lane & 15, quad = lane >> 4;
    const unsigned* QB = (const unsigned*)(tw + TW_QB);
    const unsigned* KB = (const unsigned*)(tw + TW_KB);
    bf16x8 qbf[2], kbf[4];
    #pragma unroll
    for (int ks = 0; ks < 2; ++ks)
        qbf[ks] = ldfrag((const unsigned short*)&QB[((ks*4 + w)*64 + lane)*4]);
    #pragma unroll
    for (int nb = 0; nb < 4; ++nb)
        kbf[nb] = ldfrag((const unsigned short*)&KB[((w*4 + nb)*64 + lane)*4]);
    __syncthreads();

    int cq = w*16 + l16;
    float bq = in_b[cq];
    #pragma unroll
    for (int mb = 0; mb < 5; ++mb) {
        bf16x8 a0 = ldfrag(&sQF[(mb*16 + l16)*72 + quad*8]);
        bf16x8 a1 = ldfrag(&sQF[(mb*16 + l16)*72 + 32 + quad*8]);
        f32x4 acc = {0.f, 0.f, 0.f, 0.f};
        acc = __builtin_amdgcn_mfma_f32_16x16x32_bf16(a0, qbf[0], acc, 0, 0, 0);
        acc = __builtin_amdgcn_mfma_f32_16x16x32_bf16(a1, qbf[1], acc, 0, 0, 0);
        #pragma unroll
        for (int reg = 0; reg < 4; ++reg) {
            int row = mb*16 + quad*4 + reg;
            sQ[row*72 + cq] = (unsigned short)f2bf((acc[reg] + bq) * 0.25f);
        }
    }
    // per-head M GEMM: head h = w reads exactly the cols it wrote (in-order, no barrier)
    #pragma unroll
    for (int mb = 0; mb < 5; ++mb) {
        bf16x8 a = {0,0,0,0,0,0,0,0};
        if (quad < 2) a = ldfrag(&sQ[(mb*16 + l16)*72 + w*16 + quad*8]);
        f32x4 acc[4];
        #pragma unroll
        for (int nb = 0; nb < 4; ++nb) {
            f32x4 z = {0.f, 0.f, 0.f, 0.f};
            acc[nb] = __builtin_amdgcn_mfma_f32_16x16x32_bf16(a, kbf[nb], z, 0, 0, 0);
        }
        #pragma unroll
        for (int nb = 0; nb < 4; ++nb)
            #pragma unroll
            for (int reg = 0; reg < 4; ++reg) {
                int r = base + mb*16 + quad*4 + reg, j = nb*16 + l16;
                M_all[(size_t)r*256 + j*4 + w] = (unsigned short)f2bf(acc[nb][reg]);
            }
    }
}

// ---------------------------------------------------------------------------
// attn (unchanged from R4): one wave/query, pipelined gather, factored scores.
// ---------------------------------------------------------------------------
__global__ __launch_bounds__(64, 2) void attn_kernel(
    const float* __restrict__ vfeat, const float* __restrict__ vcoord,
    const float* __restrict__ qcoord, const int* __restrict__ kidx,
    const float* __restrict__ kpos_w, const float* __restrict__ kpos_b,
    const float* __restrict__ in_b, const float* __restrict__ out_b,
    const float* __restrict__ tw, const unsigned short* __restrict__ M_all,
    float* __restrict__ att_out)
{
    __shared__ __align__(16) float skf[KK*68];
    __shared__ __align__(16) float reg1[256];
    __shared__ __align__(16) float sT[4*65];
    int n = blockIdx.x, c = threadIdx.x;
    int l16 = c & 15, h = c >> 4;
    float* sM   = reg1;
    float* sP   = reg1;
    float* sctx = reg1 + 192;

    {
        uint2 mu = ((const uint2*)(M_all + (size_t)n*256))[c];
        float4 mf;
        mf.x = __uint_as_float(mu.x << 16);
        mf.y = __uint_as_float(mu.x & 0xffff0000u);
        mf.z = __uint_as_float(mu.y << 16);
        mf.w = __uint_as_float(mu.y & 0xffff0000u);
        *(float4*)&sM[4*c] = mf;
    }

    float qc0 = qcoord[n*3+0], qc1 = qcoord[n*3+1], qc2 = qcoord[n*3+2];
    int kread = c < 48 ? c : 47;
    int idxv = kidx[(size_t)n*KK + kread];
    int sfe = idxv < 0 ? 0 : idxv;
    float rl0 = vcoord[sfe*3+0] - qc0;
    float rl1 = vcoord[sfe*3+1] - qc1;
    float rl2 = vcoord[sfe*3+2] - qc2;

    float4 wA  = *(const float4*)(kpos_w + 12*l16 + 0);
    float4 wB  = *(const float4*)(kpos_w + 12*l16 + 4);
    float4 wC  = *(const float4*)(kpos_w + 12*l16 + 8);
    float4 kb4 = *(const float4*)(kpos_b + 4*l16);

    float4 fv[12];
    #pragma unroll
    for (int i = 0; i < 12; ++i) {
        int row = 4*i + h;
        int si = __shfl(idxv, row);
        si = si < 0 ? 0 : si;
        fv[i] = *(const float4*)(vfeat + (size_t)si*64 + 4*l16);
    }
    #pragma unroll
    for (int i = 0; i < 12; ++i) {
        int row = 4*i + h;
        float rr0 = __shfl(rl0, row), rr1 = __shfl(rl1, row), rr2 = __shfl(rl2, row);
        float4 o = fv[i];
        o.x += fmaxf(fmaf(wA.x, rr0, fmaf(wA.y, rr1, fmaf(wA.z, rr2, kb4.x))), 0.0f);
        o.y += fmaxf(fmaf(wA.w, rr0, fmaf(wB.x, rr1, fmaf(wB.y, rr2, kb4.y))), 0.0f);
        o.z += fmaxf(fmaf(wB.z, rr0, fmaf(wB.w, rr1, fmaf(wC.x, rr2, kb4.z))), 0.0f);
        o.w += fmaxf(fmaf(wC.y, rr0, fmaf(wC.z, rr1, fmaf(wC.w, rr2, kb4.w))), 0.0f);
        *(float4*)&skf[row*68 + 4*l16] = o;
    }

    int i0 = __shfl(idxv, l16), i1 = __shfl(idxv, l16 + 16), i2 = __shfl(idxv, l16 + 32);
    float S0 = 0, S1 = 0, S2 = 0;
    #pragma unroll
    for (int j4 = 0; j4 < 16; ++j4) {
        float4 a = *(const float4*)&skf[ l16       *68 + 4*j4];
        float4 b = *(const float4*)&skf[(l16 + 16) *68 + 4*j4];
        float4 d = *(const float4*)&skf[(l16 + 32) *68 + 4*j4];
        float m0 = sM[(4*j4 + 0)*4 + h], m1 = sM[(4*j4 + 1)*4 + h];
        float m2 = sM[(4*j4 + 2)*4 + h], m3 = sM[(4*j4 + 3)*4 + h];
        S0 = fmaf(a.x, m0, S0); S0 = fmaf(a.y, m1, S0); S0 = fmaf(a.z, m2, S0); S0 = fmaf(a.w, m3, S0);
        S1 = fmaf(b.x, m0, S1); S1 = fmaf(b.y, m1, S1); S1 = fmaf(b.z, m2, S1); S1 = fmaf(b.w, m3, S1);
        S2 = fmaf(d.x, m0, S2); S2 = fmaf(d.y, m1, S2); S2 = fmaf(d.z, m2, S2); S2 = fmaf(d.w, m3, S2);
    }
    if (i0 < 0) S0 = -INFINITY;
    if (i1 < 0) S1 = -INFINITY;
    if (i2 < 0) S2 = -INFINITY;

    float mx = fmaxf(S0, fmaxf(S1, S2));
    #pragma unroll
    for (int off = 8; off >= 1; off >>= 1) mx = fmaxf(mx, __shfl_xor(mx, off, 16));
    float e0 = __expf(S0 - mx), e1 = __expf(S1 - mx), e2 = __expf(S2 - mx);
    float es = e0 + e1 + e2;
    #pragma unroll
    for (int off = 8; off >= 1; off >>= 1) es += __shfl_xor(es, off, 16);
    float rinv = 1.0f / es;
    sP[ l16       *4 + h] = e0 * rinv;
    sP[(l16 + 16) *4 + h] = e1 * rinv;
    sP[(l16 + 32) *4 + h] = e2 * rinv;

    float T0 = 0, T1 = 0, T2 = 0, T3 = 0;
    #pragma unroll 8
    for (int k = 0; k < KK; ++k) {
        float kf = skf[k*68 + c];
        float4 p = *(const float4*)&sP[k*4];
        T0 = fmaf(p.x, kf, T0); T1 = fmaf(p.y, kf, T1);
        T2 = fmaf(p.z, kf, T2); T3 = fmaf(p.w, kf, T3);
    }
    sT[0*65 + c] = T0; sT[1*65 + c] = T1; sT[2*65 + c] = T2; sT[3*65 + c] = T3;

    const float* WvT = tw + TW_WVT;
    float ctx = in_b[128 + c];
    #pragma unroll 8
    for (int cp = 0; cp < 64; ++cp)
        ctx = fmaf(sT[h*65 + cp], WvT[cp*64 + c], ctx);
    sctx[c] = ctx;

    const float* WoT = tw + TW_WOT;
    float att = out_b[c];
    #pragma unroll 8
    for (int j = 0; j < 64; ++j)
        att = fmaf(sctx[j], WoT[j*64 + c], att);
    att_out[(size_t)n*64 + c] = att;
}

// ---------------------------------------------------------------------------
// ffn (MFMA): y = att + lin2(relu(lin1(att))), in place; BN1 stats.
// 80 queries/block, 4 waves. GEMM1 N=256 (wave: 4 n-subtiles), GEMM2 N=64.
// ---------------------------------------------------------------------------
__global__ __launch_bounds__(256) void ffn_kernel(
    const float* __restrict__ tw, const float* __restrict__ lin1_b,
    const float* __restrict__ lin2_b, float* __restrict__ att_y,
    float* __restrict__ sum1, float* __restrict__ sumsq1)
{
    __shared__ __align__(16) unsigned short sA[80*72];
    __shared__ __align__(16) unsigned short sH[80*264];
    int t = threadIdx.x, base = blockIdx.x * 80;
    #pragma unroll
    for (int i = 0; i < 5; ++i) {
        int e = i*1024 + t*4, r = e >> 6, col = e & 63;
        float4 v = *(const float4*)&att_y[(size_t)(base + r)*64 + col];
        uint2 p; p.x = pk2(v.x, v.y); p.y = pk2(v.z, v.w);
        *(uint2*)&sA[r*72 + col] = p;
    }
    int w = t >> 6, lane = t & 63, l16 = lane & 15, quad = lane >> 4;
    const unsigned* L1B = (const unsigned*)(tw + TW_L1B);
    const unsigned* L2B = (const unsigned*)(tw + TW_L2B);
    bf16x8 b1f[2][4], b2f[8];
    #pragma unroll
    for (int ks = 0; ks < 2; ++ks)
        #pragma unroll
        for (int nb = 0; nb < 4; ++nb)
            b1f[ks][nb] = ldfrag((const unsigned short*)&L1B[((ks*16 + w*4 + nb)*64 + lane)*4]);
    #pragma unroll
    for (int ks = 0; ks < 8; ++ks)
        b2f[ks] = ldfrag((const unsigned short*)&L2B[((ks*4 + w)*64 + lane)*4]);
    __syncthreads();

    #pragma unroll
    for (int mb = 0; mb < 5; ++mb) {
        bf16x8 a0 = ldfrag(&sA[(mb*16 + l16)*72 + quad*8]);
        bf16x8 a1 = ldfrag(&sA[(mb*16 + l16)*72 + 32 + quad*8]);
        #pragma unroll
        for (int nb = 0; nb < 4; ++nb) {
            f32x4 acc = {0.f, 0.f, 0.f, 0.f};
            acc = __builtin_amdgcn_mfma_f32_16x16x32_bf16(a0, b1f[0][nb], acc, 0, 0, 0);
            acc = __builtin_amdgcn_mfma_f32_16x16x32_bf16(a1, b1f[1][nb], acc, 0, 0, 0);
            int f = w*64 + nb*16 + l16;
            float bias = lin1_b[f];
            #pragma unroll
            for (int reg = 0; reg < 4; ++reg) {
                int row = mb*16 + quad*4 + reg;
                sH[row*264 + f] = (unsigned short)f2bf(fmaxf(acc[reg] + bias, 0.0f));
            }
        }
    }
    __syncthreads();

    int c = w*16 + l16;
    float lb2 = lin2_b[c];
    float s = 0.f, ss = 0.f;
    #pragma unroll
    for (int mb = 0; mb < 5; ++mb) {
        f32x4 acc = {0.f, 0.f, 0.f, 0.f};
        #pragma unroll
        for (int ks = 0; ks < 8; ++ks) {
            bf16x8 a = ldfrag(&sH[(mb*16 + l16)*264 + ks*32 + quad*8]);
            acc = __builtin_amdgcn_mfma_f32_16x16x32_bf16(a, b2f[ks], acc, 0, 0, 0);
        }
        #pragma unroll
        for (int reg = 0; reg < 4; ++reg) {
            int r = base + mb*16 + quad*4 + reg;
            float y = att_y[(size_t)r*64 + c] + lb2 + acc[reg];
            att_y[(size_t)r*64 + c] = y;
            s += y; ss = fmaf(y, y, ss);
        }
    }
    s  += __shfl_xor(s, 16);  s  += __shfl_xor(s, 32);
    ss += __shfl_xor(ss, 16); ss += __shfl_xor(ss, 32);
    if (lane < 16) {
        atomicAdd(&sum1[c], s);
        atomicAdd(&sumsq1[c], ss);
    }
}

// ---------------------------------------------------------------------------
// linout (MFMA): xn = bn1(y) staged bf16; z = xn @ Ol^T + ob -> d_out; BN2 stats.
// ---------------------------------------------------------------------------
__global__ __launch_bounds__(256) void linout_kernel(
    const float* __restrict__ tw, const float* __restrict__ outl_b,
    const float* __restrict__ norm_g, const float* __restrict__ norm_b,
    const float* __restrict__ sum1, const float* __restrict__ sumsq1,
    const float* __restrict__ y, float* __restrict__ z_out,
    float* __restrict__ sum2, float* __restrict__ sumsq2)
{
    __shared__ __align__(16) unsigned short sX[80*72];
    int t = threadIdx.x, base = blockIdx.x * 80;
    int colq = (t*4) & 63;
    const float invN = 1.0f / 20000.0f;
    float4 sm = *(const float4*)&sum1[colq];
    float4 sq = *(const float4*)&sumsq1[colq];
    float4 g  = *(const float4*)&norm_g[colq];
    float4 bb = *(const float4*)&norm_b[colq];
    float mu0 = sm.x*invN, mu1 = sm.y*invN, mu2 = sm.z*invN, mu3 = sm.w*invN;
    float a0 = g.x / sqrtf(fmaf(-mu0, mu0, sq.x*invN) + 1e-5f);
    float a1 = g.y / sqrtf(fmaf(-mu1, mu1, sq.y*invN) + 1e-5f);
    float a2 = g.z / sqrtf(fmaf(-mu2, mu2, sq.z*invN) + 1e-5f);
    float a3 = g.w / sqrtf(fmaf(-mu3, mu3, sq.w*invN) + 1e-5f);
    float b0 = fmaf(-mu0, a0, bb.x), b1 = fmaf(-mu1, a1, bb.y);
    float b2 = fmaf(-mu2, a2, bb.z), b3 = fmaf(-mu3, a3, bb.w);
    #pragma unroll
    for (int i = 0; i < 5; ++i) {
        int e = i*1024 + t*4, r = e >> 6;
        float4 v = *(const float4*)&y[(size_t)(base + r)*64 + colq];
        uint2 p;
        p.x = pk2(fmaf(v.x, a0, b0), fmaf(v.y, a1, b1));
        p.y = pk2(fmaf(v.z, a2, b2), fmaf(v.w, a3, b3));
        *(uint2*)&sX[r*72 + colq] = p;
    }
    int w = t >> 6, lane = t & 63, l16 = lane & 15, quad = lane >> 4;
    const unsigned* OLB = (const unsigned*)(tw + TW_OLB);
    bf16x8 obf[2];
    #pragma unroll
    for (int ks = 0; ks < 2; ++ks)
        obf[ks] = ldfrag((const unsigned short*)&OLB[((ks*4 + w)*64 + lane)*4]);
    __syncthreads();

    int co = w*16 + l16;
    float ob = outl_b[co];
    float s = 0.f, ss = 0.f;
    #pragma unroll
    for (int mb = 0; mb < 5; ++mb) {
        bf16x8 x0 = ldfrag(&sX[(mb*16 + l16)*72 + quad*8]);
        bf16x8 x1 = ldfrag(&sX[(mb*16 + l16)*72 + 32 + quad*8]);
        f32x4 acc = {0.f, 0.f, 0.f, 0.f};
        acc = __builtin_amdgcn_mfma_f32_16x16x32_bf16(x0, obf[0], acc, 0, 0, 0);
        acc = __builtin_amdgcn_mfma_f32_16x16x32_bf16(x1, obf[1], acc, 0, 0, 0);
        #pragma unroll
        for (int reg = 0; reg < 4; ++reg) {
            int r = base + mb*16 + quad*4 + reg;
            float zv = acc[reg] + ob;
            z_out[(size_t)r*64 + co] = zv;
            s += zv; ss = fmaf(zv, zv, ss);
        }
    }
    s  += __shfl_xor(s, 16);  s  += __shfl_xor(s, 32);
    ss += __shfl_xor(ss, 16); ss += __shfl_xor(ss, 32);
    if (lane < 16) {
        atomicAdd(&sum2[co], s);
        atomicAdd(&sumsq2[co], ss);
    }
}

// ---------------------------------------------------------------------------
// out = relu(bn2(z)) in place.
// ---------------------------------------------------------------------------
__global__ void final_kernel(float* __restrict__ z,
    const float* __restrict__ sum2, const float* __restrict__ sumsq2,
    const float* __restrict__ obn_g, const float* __restrict__ obn_b)
{
    int i = blockIdx.x*blockDim.x + threadIdx.x;
    if (i >= N_Q*64/4) return;
    int o4 = (i*4) & 63;
    float4 sm = *(const float4*)&sum2[o4];
    float4 sq = *(const float4*)&sumsq2[o4];
    float4 g  = *(const float4*)&obn_g[o4];
    float4 b  = *(const float4*)&obn_b[o4];
    const float invN = 1.0f / 20000.0f;
    float mux = sm.x*invN, muy = sm.y*invN, muz = sm.z*invN, muw = sm.w*invN;
    float ax = g.x / sqrtf(fmaf(-mux, mux, sq.x*invN) + 1e-5f);
    float ay = g.y / sqrtf(fmaf(-muy, muy, sq.y*invN) + 1e-5f);
    float az = g.z / sqrtf(fmaf(-muz, muz, sq.z*invN) + 1e-5f);
    float aw = g.w / sqrtf(fmaf(-muw, muw, sq.w*invN) + 1e-5f);
    float4 v = ((float4*)z)[i];
    v.x = fmaxf(fmaf(v.x - mux, ax, b.x), 0.0f);
    v.y = fmaxf(fmaf(v.y - muy, ay, b.y), 0.0f);
    v.z = fmaxf(fmaf(v.z - muz, az, b.z), 0.0f);
    v.w = fmaxf(fmaf(v.w - muw, aw, b.w), 0.0f);
    ((float4*)z)[i] = v;
}

extern "C" void kernel_launch(void* const* d_in, const int* in_sizes, int n_in,
                              void* d_out, int out_size, void* d_ws, size_t ws_size,
                              hipStream_t stream)
{
    const float* vfeat  = (const float*)d_in[0];
    const float* vcoord = (const float*)d_in[1];
    const float* qcoord = (const float*)d_in[2];
    const int*   kidx   = (const int*)d_in[3];
    const float* q_w    = (const float*)d_in[4];
    const float* q_b    = (const float*)d_in[5];
    const float* kpos_w = (const float*)d_in[6];
    const float* kpos_b = (const float*)d_in[7];
    const float* in_w   = (const float*)d_in[8];
    const float* in_b   = (const float*)d_in[9];
    const float* out_w  = (const float*)d_in[10];
    const float* out_b  = (const float*)d_in[11];
    const float* lin1_w = (const float*)d_in[12];
    const float* lin1_b = (const float*)d_in[13];
    const float* lin2_w = (const float*)d_in[14];
    const float* lin2_b = (const float*)d_in[15];
    const float* norm_g = (const float*)d_in[16];
    const float* norm_b = (const float*)d_in[17];
    const float* outl_w = (const float*)d_in[18];
    const float* outl_b = (const float*)d_in[19];
    const float* obn_g  = (const float*)d_in[20];
    const float* obn_b  = (const float*)d_in[21];

    float* ws = (float*)d_ws;
    float* tw = ws;
    float* stats = ws + ST_OFF;
    float* sum1 = stats, *sumsq1 = stats + 64, *sum2 = stats + 128, *sumsq2 = stats + 192;
    unsigned short* M_all = (unsigned short*)(ws + M_OFF);
    float* xd = (float*)d_out;    // att -> y -> z -> out, all in place

    hipMemsetAsync(stats, 0, 256*sizeof(float), stream);
    prep_weights<<<128, 256, 0, stream>>>(in_w, out_w, lin1_w, lin2_w, outl_w, tw);
    m_kernel<<<250, 256, 0, stream>>>(qcoord, q_w, q_b, in_b, tw, M_all);
    attn_kernel<<<N_Q, 64, 0, stream>>>(vfeat, vcoord, qcoord, kidx, kpos_w, kpos_b,
                                        in_b, out_b, tw, M_all, xd);
    ffn_kernel<<<250, 256, 0, stream>>>(tw, lin1_b, lin2_b, xd, sum1, sumsq1);
    linout_kernel<<<250, 256, 0, stream>>>(tw, outl_b, norm_g, norm_b, sum1, sumsq1,
                                           xd, xd, sum2, sumsq2);
    final_kernel<<<1250, 256, 0, stream>>>(xd, sum2, sumsq2, obn_g, obn_b);
}

// Round 6
// 203.064 us; speedup vs baseline: 2.0655x; 1.0927x over previous
//
#include <hip/hip_runtime.h>
#include <math.h>

#define N_Q 20000
#define KK 48
#define CC 64
#define FFD 256

// ws float offsets
#define TW_WOT   0        // 4096 f32: WoT[j*64+c] = out_w[c*64+j]        (attn)
#define TW_WVT   4096     // 4096 f32: WvT[cp*64+c] = in_w[(128+c)*64+cp] (attn)
#define TW_L1B   8192     // 8192 u32: lin1 B-frags  [ks2][nb16][lane64][4]
#define TW_L2B   16384    // 8192 u32: lin2 B-frags  [ks8][nb4][lane64][4]
#define TW_OLB   24576    // 2048 u32: outl B-frags  [ks2][nb4][lane64][4]
#define TW_QB    26624    // 2048 u32: Wq   B-frags  [ks2][nb4][lane64][4]
#define TW_KB    28672    // 4096 u32: Wk   B-frags  [h4][nb4][lane64][4] (k>=16 zero)
#define ST_OFF   32768    // 256 f32: sum1,sumsq1,sum2,sumsq2
#define M_OFF    33024    // bf16 M_all[n][j*4+h], 20000*256 ushorts (2,560,000 f32-equiv)
#define VF_OFF   2593024  // bf16 vfeat table, 80000*64 ushorts (10.24 MB)

typedef short bf16x8 __attribute__((ext_vector_type(8)));
typedef float f32x4  __attribute__((ext_vector_type(4)));

__device__ __forceinline__ unsigned f2bf(float f) {
    unsigned u = __float_as_uint(f);
    return (u + 0x7fffu + ((u >> 16) & 1u)) >> 16;          // RNE to bf16
}
__device__ __forceinline__ unsigned pk2(float a, float b) {
    return f2bf(a) | (f2bf(b) << 16);
}
__device__ __forceinline__ float bflo(unsigned u) { return __uint_as_float(u << 16); }
__device__ __forceinline__ float bfhi(unsigned u) { return __uint_as_float(u & 0xffff0000u); }
__device__ __forceinline__ bf16x8 ldfrag(const unsigned short* p) {
    return *(const bf16x8*)p;
}

// ---------------------------------------------------------------------------
// prep_all: weight transposes/fragment packs + bf16 vfeat table + stats zero.
// grid 5120 x 256 (threads 0..1,310,719; vfeat needs 1,280,000).
// ---------------------------------------------------------------------------
__global__ void prep_all(const float* __restrict__ in_w,
                         const float* __restrict__ out_w,
                         const float* __restrict__ lin1_w,
                         const float* __restrict__ lin2_w,
                         const float* __restrict__ outl_w,
                         const float* __restrict__ vfeat,
                         float* __restrict__ tw,
                         unsigned short* __restrict__ vfeat_bf,
                         float* __restrict__ stats)
{
    int t = blockIdx.x * 256 + threadIdx.x;
    unsigned* twu = (unsigned*)tw;
    if (t < 1280000) {                          // vfeat -> bf16 (4 elems/thread)
        float4 v = ((const float4*)vfeat)[t];
        uint2 p; p.x = pk2(v.x, v.y); p.y = pk2(v.z, v.w);
        ((uint2*)vfeat_bf)[t] = p;
    }
    if (t < 256) stats[t] = 0.0f;
    if (t < 4096) {
        int c = t >> 6, j = t & 63;
        tw[TW_WOT + j*64 + c] = out_w[c*64 + j];
    } else if (t < 8192) {
        int i = t - 4096, cp = i >> 6, c = i & 63;
        tw[TW_WVT + cp*64 + c] = in_w[(128 + c)*64 + cp];
    } else if (t < 16384) {                    // L1B: H = att @ lin1_w^T
        int p = t - 8192;
        int j2 = p & 3, lane = (p >> 2) & 63, nb = (p >> 8) & 15, ks = p >> 12;
        int n = nb*16 + (lane & 15), k = ks*32 + (lane >> 4)*8 + 2*j2;
        twu[TW_L1B + p] = pk2(lin1_w[n*64 + k], lin1_w[n*64 + k + 1]);
    } else if (t < 24576) {                    // L2B: Y = H @ lin2_w^T
        int p = t - 16384;
        int j2 = p & 3, lane = (p >> 2) & 63, nb = (p >> 8) & 3, ks = p >> 10;
        int n = nb*16 + (lane & 15), k = ks*32 + (lane >> 4)*8 + 2*j2;
        twu[TW_L2B + p] = pk2(lin2_w[n*256 + k], lin2_w[n*256 + k + 1]);
    } else if (t < 26624) {                    // OLB: z = xn @ outl_w^T
        int p = t - 24576;
        int j2 = p & 3, lane = (p >> 2) & 63, nb = (p >> 8) & 3, ks = p >> 10;
        int n = nb*16 + (lane & 15), k = ks*32 + (lane >> 4)*8 + 2*j2;
        twu[TW_OLB + p] = pk2(outl_w[n*64 + k], outl_w[n*64 + k + 1]);
    } else if (t < 28672) {                    // QB: q = qf @ Wq^T
        int p = t - 26624;
        int j2 = p & 3, lane = (p >> 2) & 63, nb = (p >> 8) & 3, ks = p >> 10;
        int n = nb*16 + (lane & 15), k = ks*32 + (lane >> 4)*8 + 2*j2;
        twu[TW_QB + p] = pk2(in_w[n*64 + k], in_w[n*64 + k + 1]);
    } else if (t < 32768) {                    // KB: M = q @ Wk (per head, K=16 zero-pad)
        int p = t - 28672;
        int j2 = p & 3, lane = (p >> 2) & 63, nb = (p >> 8) & 3, h = p >> 10;
        int j = nb*16 + (lane & 15), k = (lane >> 4)*8 + 2*j2;
        unsigned u = 0;
        if (k < 16)
            u = pk2(in_w[(64 + h*16 + k)*64 + j], in_w[(64 + h*16 + k + 1)*64 + j]);
        twu[TW_KB + p] = u;
    }
}

// ---------------------------------------------------------------------------
// m_kernel (MFMA): 80 queries/block. qf=relu(qc@qw^T+qb) staged bf16 ->
// q GEMM (wave w owns cols w*16..+15) -> per-head M GEMM (head = wave).
// ---------------------------------------------------------------------------
__global__ __launch_bounds__(256) void m_kernel(
    const float* __restrict__ qcoord, const float* __restrict__ q_w,
    const float* __restrict__ q_b, const float* __restrict__ in_b,
    const float* __restrict__ tw, unsigned short* __restrict__ M_all)
{
    __shared__ __align__(16) unsigned short sQF[80*72];
    __shared__ __align__(16) unsigned short sQ[80*72];
    int t = threadIdx.x, base = blockIdx.x * 80;
    int colq = (t*4) & 63;
    float qwv[12];
    #pragma unroll
    for (int j = 0; j < 12; ++j) qwv[j] = q_w[colq*3 + j];
    float4 qb4 = *(const float4*)&q_b[colq];
    #pragma unroll
    for (int i = 0; i < 5; ++i) {
        int e = i*1024 + t*4, r = e >> 6, n = base + r;
        float c0 = qcoord[n*3], c1 = qcoord[n*3+1], c2 = qcoord[n*3+2];
        float f0 = fmaxf(fmaf(qwv[2],  c2, fmaf(qwv[1],  c1, fmaf(qwv[0], c0, qb4.x))), 0.f);
        float f1 = fmaxf(fmaf(qwv[5],  c2, fmaf(qwv[4],  c1, fmaf(qwv[3], c0, qb4.y))), 0.f);
        float f2 = fmaxf(fmaf(qwv[8],  c2, fmaf(qwv[7],  c1, fmaf(qwv[6], c0, qb4.z))), 0.f);
        float f3 = fmaxf(fmaf(qwv[11], c2, fmaf(qwv[10], c1, fmaf(qwv[9], c0, qb4.w))), 0.f);
        uint2 p; p.x = pk2(f0, f1); p.y = pk2(f2, f3);
        *(uint2*)&sQF[r*72 + colq] = p;
    }
    int w = t >> 6, lane = t & 63, l16 = lane & 15, quad = lane >> 4;
    const unsigned* QB = (const unsigned*)(tw + TW_QB);
    const unsigned* KB = (const unsigned*)(tw + TW_KB);
    bf16x8 qbf[2], kbf[4];
    #pragma unroll
    for (int ks = 0; ks < 2; ++ks)
        qbf[ks] = ldfrag((const unsigned short*)&QB[((ks*4 + w)*64 + lane)*4]);
    #pragma unroll
    for (int nb = 0; nb < 4; ++nb)
        kbf[nb] = ldfrag((const unsigned short*)&KB[((w*4 + nb)*64 + lane)*4]);
    __syncthreads();

    int cq = w*16 + l16;
    float bq = in_b[cq];
    #pragma unroll
    for (int mb = 0; mb < 5; ++mb) {
        bf16x8 a0 = ldfrag(&sQF[(mb*16 + l16)*72 + quad*8]);
        bf16x8 a1 = ldfrag(&sQF[(mb*16 + l16)*72 + 32 + quad*8]);
        f32x4 acc = {0.f, 0.f, 0.f, 0.f};
        acc = __builtin_amdgcn_mfma_f32_16x16x32_bf16(a0, qbf[0], acc, 0, 0, 0);
        acc = __builtin_amdgcn_mfma_f32_16x16x32_bf16(a1, qbf[1], acc, 0, 0, 0);
        #pragma unroll
        for (int reg = 0; reg < 4; ++reg) {
            int row = mb*16 + quad*4 + reg;
            sQ[row*72 + cq] = (unsigned short)f2bf((acc[reg] + bq) * 0.25f);
        }
    }
    // per-head M GEMM: head h = w reads exactly the cols it wrote (in-order)
    #pragma unroll
    for (int mb = 0; mb < 5; ++mb) {
        bf16x8 a = {0,0,0,0,0,0,0,0};
        if (quad < 2) a = ldfrag(&sQ[(mb*16 + l16)*72 + w*16 + quad*8]);
        f32x4 acc[4];
        #pragma unroll
        for (int nb = 0; nb < 4; ++nb) {
            f32x4 z = {0.f, 0.f, 0.f, 0.f};
            acc[nb] = __builtin_amdgcn_mfma_f32_16x16x32_bf16(a, kbf[nb], z, 0, 0, 0);
        }
        #pragma unroll
        for (int nb = 0; nb < 4; ++nb)
            #pragma unroll
            for (int reg = 0; reg < 4; ++reg) {
                int r = base + mb*16 + quad*4 + reg, j = nb*16 + l16;
                M_all[(size_t)r*256 + j*4 + w] = (unsigned short)f2bf(acc[nb][reg]);
            }
    }
}

// ---------------------------------------------------------------------------
// attn: one wave/query. bf16 gather (8B/lane) -> bf16 KF in LDS (7.9 KB
// total => 20 blocks/CU). Factored scores, softmax, T=P@KF, ctx, att.
// sT aliases dead skf. Barrier-free (single wave, in-order LDS).
// ---------------------------------------------------------------------------
__global__ __launch_bounds__(64, 4) void attn_kernel(
    const unsigned short* __restrict__ vfeat_bf, const float* __restrict__ vcoord,
    const float* __restrict__ qcoord, const int* __restrict__ kidx,
    const float* __restrict__ kpos_w, const float* __restrict__ kpos_b,
    const float* __restrict__ in_b, const float* __restrict__ out_b,
    const float* __restrict__ tw, const unsigned short* __restrict__ M_all,
    float* __restrict__ att_out)
{
    __shared__ __align__(16) unsigned short skf[KK*72];  // 6912 B, bf16, pitch 72
    __shared__ __align__(16) float reg1[256];            // sM | sP | sctx
    int n = blockIdx.x, c = threadIdx.x;
    int l16 = c & 15, h = c >> 4;
    float* sM   = reg1;          // 256 f, dead after score loop
    float* sP   = reg1;          // 192 f, written post-softmax
    float* sctx = reg1 + 192;    // 64 f
    float* sT   = (float*)skf;   // 4*65 f, aliases skf (dead after T loop)

    // stage M (bf16 -> f32)
    {
        uint2 mu = ((const uint2*)(M_all + (size_t)n*256))[c];
        float4 mf;
        mf.x = bflo(mu.x); mf.y = bfhi(mu.x);
        mf.z = bflo(mu.y); mf.w = bfhi(mu.y);
        *(float4*)&sM[4*c] = mf;
    }

    float qc0 = qcoord[n*3+0], qc1 = qcoord[n*3+1], qc2 = qcoord[n*3+2];

    // lanes 0..47: key index + relative coords
    int kread = c < 48 ? c : 47;
    int idxv = kidx[(size_t)n*KK + kread];
    int sfe = idxv < 0 ? 0 : idxv;
    float rl0 = vcoord[sfe*3+0] - qc0;
    float rl1 = vcoord[sfe*3+1] - qc1;
    float rl2 = vcoord[sfe*3+2] - qc2;

    // kpos params for this lane's 4 channels (j = 4*l16 + 0..3)
    float4 wA  = *(const float4*)(kpos_w + 12*l16 + 0);
    float4 wB  = *(const float4*)(kpos_w + 12*l16 + 4);
    float4 wC  = *(const float4*)(kpos_w + 12*l16 + 8);
    float4 kb4 = *(const float4*)(kpos_b + 4*l16);

    // ---- issue all 12 gather loads (8B/lane: 4 bf16 channels) ----
    uint2 fv[12];
    #pragma unroll
    for (int i = 0; i < 12; ++i) {
        int row = 4*i + h;
        int si = __shfl(idxv, row);
        si = si < 0 ? 0 : si;
        fv[i] = *(const uint2*)(vfeat_bf + (size_t)si*64 + 4*l16);
    }
    // ---- consume: unpack, add positional encoding, repack to bf16 LDS ----
    #pragma unroll
    for (int i = 0; i < 12; ++i) {
        int row = 4*i + h;
        float rr0 = __shfl(rl0, row), rr1 = __shfl(rl1, row), rr2 = __shfl(rl2, row);
        float g0 = bflo(fv[i].x), g1 = bfhi(fv[i].x);
        float g2 = bflo(fv[i].y), g3 = bfhi(fv[i].y);
        g0 += fmaxf(fmaf(wA.x, rr0, fmaf(wA.y, rr1, fmaf(wA.z, rr2, kb4.x))), 0.0f);
        g1 += fmaxf(fmaf(wA.w, rr0, fmaf(wB.x, rr1, fmaf(wB.y, rr2, kb4.y))), 0.0f);
        g2 += fmaxf(fmaf(wB.z, rr0, fmaf(wB.w, rr1, fmaf(wC.x, rr2, kb4.z))), 0.0f);
        g3 += fmaxf(fmaf(wC.y, rr0, fmaf(wC.z, rr1, fmaf(wC.w, rr2, kb4.w))), 0.0f);
        uint2 p; p.x = pk2(g0, g1); p.y = pk2(g2, g3);
        *(uint2*)&skf[row*72 + 4*l16] = p;
    }

    // ---- scores: lane (l16,h) computes S[h, l16], S[h, l16+16], S[h, l16+32]
    int i0 = __shfl(idxv, l16), i1 = __shfl(idxv, l16 + 16), i2 = __shfl(idxv, l16 + 32);
    float S0 = 0, S1 = 0, S2 = 0;
    #pragma unroll
    for (int j8 = 0; j8 < 8; ++j8) {
        uint2 A = *(const uint2*)&skf[ l16       *72 + 8*j8];
        uint2 A2= *(const uint2*)&skf[ l16       *72 + 8*j8 + 4];
        uint2 B = *(const uint2*)&skf[(l16 + 16) *72 + 8*j8];
        uint2 B2= *(const uint2*)&skf[(l16 + 16) *72 + 8*j8 + 4];
        uint2 D = *(const uint2*)&skf[(l16 + 32) *72 + 8*j8];
        uint2 D2= *(const uint2*)&skf[(l16 + 32) *72 + 8*j8 + 4];
        #pragma unroll
        for (int jj = 0; jj < 8; ++jj) {
            unsigned ua = (jj < 4) ? ((jj < 2) ? A.x : A.y) : ((jj < 6) ? A2.x : A2.y);
            unsigned ub = (jj < 4) ? ((jj < 2) ? B.x : B.y) : ((jj < 6) ? B2.x : B2.y);
            unsigned ud = (jj < 4) ? ((jj < 2) ? D.x : D.y) : ((jj < 6) ? D2.x : D2.y);
            float av = (jj & 1) ? bfhi(ua) : bflo(ua);
            float bv = (jj & 1) ? bfhi(ub) : bflo(ub);
            float dv = (jj & 1) ? bfhi(ud) : bflo(ud);
            float m  = sM[(8*j8 + jj)*4 + h];
            S0 = fmaf(av, m, S0);
            S1 = fmaf(bv, m, S1);
            S2 = fmaf(dv, m, S2);
        }
    }
    if (i0 < 0) S0 = -INFINITY;
    if (i1 < 0) S1 = -INFINITY;
    if (i2 < 0) S2 = -INFINITY;

    // ---- softmax across the 16 lanes of head h ----
    float mx = fmaxf(S0, fmaxf(S1, S2));
    #pragma unroll
    for (int off = 8; off >= 1; off >>= 1) mx = fmaxf(mx, __shfl_xor(mx, off, 16));
    float e0 = __expf(S0 - mx), e1 = __expf(S1 - mx), e2 = __expf(S2 - mx);
    float es = e0 + e1 + e2;
    #pragma unroll
    for (int off = 8; off >= 1; off >>= 1) es += __shfl_xor(es, off, 16);
    float rinv = 1.0f / es;
    sP[ l16       *4 + h] = e0 * rinv;
    sP[(l16 + 16) *4 + h] = e1 * rinv;
    sP[(l16 + 32) *4 + h] = e2 * rinv;

    // ---- T[h', c] = sum_k P[h',k] * KF[k,c] ----
    float T0 = 0, T1 = 0, T2 = 0, T3 = 0;
    #pragma unroll 8
    for (int k = 0; k < KK; ++k) {
        float kf = __uint_as_float(((unsigned)skf[k*72 + c]) << 16);
        float4 p = *(const float4*)&sP[k*4];
        T0 = fmaf(p.x, kf, T0); T1 = fmaf(p.y, kf, T1);
        T2 = fmaf(p.z, kf, T2); T3 = fmaf(p.w, kf, T3);
    }
    sT[0*65 + c] = T0; sT[1*65 + c] = T1; sT[2*65 + c] = T2; sT[3*65 + c] = T3;

    // ---- ctx[c] = bv[c] + sum_cp T[h(c), cp] * Wv[c, cp] ----
    const float* WvT = tw + TW_WVT;
    float ctx = in_b[128 + c];
    #pragma unroll 8
    for (int cp = 0; cp < 64; ++cp)
        ctx = fmaf(sT[h*65 + cp], WvT[cp*64 + c], ctx);
    sctx[c] = ctx;

    // ---- att[c] = bo[c] + sum_j ctx[j] * Wo[c, j] ----
    const float* WoT = tw + TW_WOT;
    float att = out_b[c];
    #pragma unroll 8
    for (int j = 0; j < 64; ++j)
        att = fmaf(sctx[j], WoT[j*64 + c], att);
    att_out[(size_t)n*64 + c] = att;
}

// ---------------------------------------------------------------------------
// ffn (MFMA): y = att + lin2(relu(lin1(att))), in place; BN1 stats.
// ---------------------------------------------------------------------------
__global__ __launch_bounds__(256) void ffn_kernel(
    const float* __restrict__ tw, const float* __restrict__ lin1_b,
    const float* __restrict__ lin2_b, float* __restrict__ att_y,
    float* __restrict__ sum1, float* __restrict__ sumsq1)
{
    __shared__ __align__(16) unsigned short sA[80*72];
    __shared__ __align__(16) unsigned short sH[80*264];
    int t = threadIdx.x, base = blockIdx.x * 80;
    #pragma unroll
    for (int i = 0; i < 5; ++i) {
        int e = i*1024 + t*4, r = e >> 6, col = e & 63;
        float4 v = *(const float4*)&att_y[(size_t)(base + r)*64 + col];
        uint2 p; p.x = pk2(v.x, v.y); p.y = pk2(v.z, v.w);
        *(uint2*)&sA[r*72 + col] = p;
    }
    int w = t >> 6, lane = t & 63, l16 = lane & 15, quad = lane >> 4;
    const unsigned* L1B = (const unsigned*)(tw + TW_L1B);
    const unsigned* L2B = (const unsigned*)(tw + TW_L2B);
    bf16x8 b1f[2][4], b2f[8];
    #pragma unroll
    for (int ks = 0; ks < 2; ++ks)
        #pragma unroll
        for (int nb = 0; nb < 4; ++nb)
            b1f[ks][nb] = ldfrag((const unsigned short*)&L1B[((ks*16 + w*4 + nb)*64 + lane)*4]);
    #pragma unroll
    for (int ks = 0; ks < 8; ++ks)
        b2f[ks] = ldfrag((const unsigned short*)&L2B[((ks*4 + w)*64 + lane)*4]);
    __syncthreads();

    #pragma unroll
    for (int mb = 0; mb < 5; ++mb) {
        bf16x8 a0 = ldfrag(&sA[(mb*16 + l16)*72 + quad*8]);
        bf16x8 a1 = ldfrag(&sA[(mb*16 + l16)*72 + 32 + quad*8]);
        #pragma unroll
        for (int nb = 0; nb < 4; ++nb) {
            f32x4 acc = {0.f, 0.f, 0.f, 0.f};
            acc = __builtin_amdgcn_mfma_f32_16x16x32_bf16(a0, b1f[0][nb], acc, 0, 0, 0);
            acc = __builtin_amdgcn_mfma_f32_16x16x32_bf16(a1, b1f[1][nb], acc, 0, 0, 0);
            int f = w*64 + nb*16 + l16;
            float bias = lin1_b[f];
            #pragma unroll
            for (int reg = 0; reg < 4; ++reg) {
                int row = mb*16 + quad*4 + reg;
                sH[row*264 + f] = (unsigned short)f2bf(fmaxf(acc[reg] + bias, 0.0f));
            }
        }
    }
    __syncthreads();

    int c = w*16 + l16;
    float lb2 = lin2_b[c];
    float s = 0.f, ss = 0.f;
    #pragma unroll
    for (int mb = 0; mb < 5; ++mb) {
        f32x4 acc = {0.f, 0.f, 0.f, 0.f};
        #pragma unroll
        for (int ks = 0; ks < 8; ++ks) {
            bf16x8 a = ldfrag(&sH[(mb*16 + l16)*264 + ks*32 + quad*8]);
            acc = __builtin_amdgcn_mfma_f32_16x16x32_bf16(a, b2f[ks], acc, 0, 0, 0);
        }
        #pragma unroll
        for (int reg = 0; reg < 4; ++reg) {
            int r = base + mb*16 + quad*4 + reg;
            float y = att_y[(size_t)r*64 + c] + lb2 + acc[reg];
            att_y[(size_t)r*64 + c] = y;
            s += y; ss = fmaf(y, y, ss);
        }
    }
    s  += __shfl_xor(s, 16);  s  += __shfl_xor(s, 32);
    ss += __shfl_xor(ss, 16); ss += __shfl_xor(ss, 32);
    if (lane < 16) {
        atomicAdd(&sum1[c], s);
        atomicAdd(&sumsq1[c], ss);
    }
}

// ---------------------------------------------------------------------------
// linout (MFMA): xn = bn1(y) staged bf16; z = xn @ Ol^T + ob -> d_out; BN2 stats.
// ---------------------------------------------------------------------------
__global__ __launch_bounds__(256) void linout_kernel(
    const float* __restrict__ tw, const float* __restrict__ outl_b,
    const float* __restrict__ norm_g, const float* __restrict__ norm_b,
    const float* __restrict__ sum1, const float* __restrict__ sumsq1,
    const float* __restrict__ y, float* __restrict__ z_out,
    float* __restrict__ sum2, float* __restrict__ sumsq2)
{
    __shared__ __align__(16) unsigned short sX[80*72];
    int t = threadIdx.x, base = blockIdx.x * 80;
    int colq = (t*4) & 63;
    const float invN = 1.0f / 20000.0f;
    float4 sm = *(const float4*)&sum1[colq];
    float4 sq = *(const float4*)&sumsq1[colq];
    float4 g  = *(const float4*)&norm_g[colq];
    float4 bb = *(const float4*)&norm_b[colq];
    float mu0 = sm.x*invN, mu1 = sm.y*invN, mu2 = sm.z*invN, mu3 = sm.w*invN;
    float a0 = g.x / sqrtf(fmaf(-mu0, mu0, sq.x*invN) + 1e-5f);
    float a1 = g.y / sqrtf(fmaf(-mu1, mu1, sq.y*invN) + 1e-5f);
    float a2 = g.z / sqrtf(fmaf(-mu2, mu2, sq.z*invN) + 1e-5f);
    float a3 = g.w / sqrtf(fmaf(-mu3, mu3, sq.w*invN) + 1e-5f);
    float b0 = fmaf(-mu0, a0, bb.x), b1 = fmaf(-mu1, a1, bb.y);
    float b2 = fmaf(-mu2, a2, bb.z), b3 = fmaf(-mu3, a3, bb.w);
    #pragma unroll
    for (int i = 0; i < 5; ++i) {
        int e = i*1024 + t*4, r = e >> 6;
        float4 v = *(const float4*)&y[(size_t)(base + r)*64 + colq];
        uint2 p;
        p.x = pk2(fmaf(v.x, a0, b0), fmaf(v.y, a1, b1));
        p.y = pk2(fmaf(v.z, a2, b2), fmaf(v.w, a3, b3));
        *(uint2*)&sX[r*72 + colq] = p;
    }
    int w = t >> 6, lane = t & 63, l16 = lane & 15, quad = lane >> 4;
    const unsigned* OLB = (const unsigned*)(tw + TW_OLB);
    bf16x8 obf[2];
    #pragma unroll
    for (int ks = 0; ks < 2; ++ks)
        obf[ks] = ldfrag((const unsigned short*)&OLB[((ks*4 + w)*64 + lane)*4]);
    __syncthreads();

    int co = w*16 + l16;
    float ob = outl_b[co];
    float s = 0.f, ss = 0.f;
    #pragma unroll
    for (int mb = 0; mb < 5; ++mb) {
        bf16x8 x0 = ldfrag(&sX[(mb*16 + l16)*72 + quad*8]);
        bf16x8 x1 = ldfrag(&sX[(mb*16 + l16)*72 + 32 + quad*8]);
        f32x4 acc = {0.f, 0.f, 0.f, 0.f};
        acc = __builtin_amdgcn_mfma_f32_16x16x32_bf16(x0, obf[0], acc, 0, 0, 0);
        acc = __builtin_amdgcn_mfma_f32_16x16x32_bf16(x1, obf[1], acc, 0, 0, 0);
        #pragma unroll
        for (int reg = 0; reg < 4; ++reg) {
            int r = base + mb*16 + quad*4 + reg;
            float zv = acc[reg] + ob;
            z_out[(size_t)r*64 + co] = zv;
            s += zv; ss = fmaf(zv, zv, ss);
        }
    }
    s  += __shfl_xor(s, 16);  s  += __shfl_xor(s, 32);
    ss += __shfl_xor(ss, 16); ss += __shfl_xor(ss, 32);
    if (lane < 16) {
        atomicAdd(&sum2[co], s);
        atomicAdd(&sumsq2[co], ss);
    }
}

// ---------------------------------------------------------------------------
// out = relu(bn2(z)) in place.
// ---------------------------------------------------------------------------
__global__ void final_kernel(float* __restrict__ z,
    const float* __restrict__ sum2, const float* __restrict__ sumsq2,
    const float* __restrict__ obn_g, const float* __restrict__ obn_b)
{
    int i = blockIdx.x*blockDim.x + threadIdx.x;
    if (i >= N_Q*64/4) return;
    int o4 = (i*4) & 63;
    float4 sm = *(const float4*)&sum2[o4];
    float4 sq = *(const float4*)&sumsq2[o4];
    float4 g  = *(const float4*)&obn_g[o4];
    float4 b  = *(const float4*)&obn_b[o4];
    const float invN = 1.0f / 20000.0f;
    float mux = sm.x*invN, muy = sm.y*invN, muz = sm.z*invN, muw = sm.w*invN;
    float ax = g.x / sqrtf(fmaf(-mux, mux, sq.x*invN) + 1e-5f);
    float ay = g.y / sqrtf(fmaf(-muy, muy, sq.y*invN) + 1e-5f);
    float az = g.z / sqrtf(fmaf(-muz, muz, sq.z*invN) + 1e-5f);
    float aw = g.w / sqrtf(fmaf(-muw, muw, sq.w*invN) + 1e-5f);
    float4 v = ((float4*)z)[i];
    v.x = fmaxf(fmaf(v.x - mux, ax, b.x), 0.0f);
    v.y = fmaxf(fmaf(v.y - muy, ay, b.y), 0.0f);
    v.z = fmaxf(fmaf(v.z - muz, az, b.z), 0.0f);
    v.w = fmaxf(fmaf(v.w - muw, aw, b.w), 0.0f);
    ((float4*)z)[i] = v;
}

extern "C" void kernel_launch(void* const* d_in, const int* in_sizes, int n_in,
                              void* d_out, int out_size, void* d_ws, size_t ws_size,
                              hipStream_t stream)
{
    const float* vfeat  = (const float*)d_in[0];
    const float* vcoord = (const float*)d_in[1];
    const float* qcoord = (const float*)d_in[2];
    const int*   kidx   = (const int*)d_in[3];
    const float* q_w    = (const float*)d_in[4];
    const float* q_b    = (const float*)d_in[5];
    const float* kpos_w = (const float*)d_in[6];
    const float* kpos_b = (const float*)d_in[7];
    const float* in_w   = (const float*)d_in[8];
    const float* in_b   = (const float*)d_in[9];
    const float* out_w  = (const float*)d_in[10];
    const float* out_b  = (const float*)d_in[11];
    const float* lin1_w = (const float*)d_in[12];
    const float* lin1_b = (const float*)d_in[13];
    const float* lin2_w = (const float*)d_in[14];
    const float* lin2_b = (const float*)d_in[15];
    const float* norm_g = (const float*)d_in[16];
    const float* norm_b = (const float*)d_in[17];
    const float* outl_w = (const float*)d_in[18];
    const float* outl_b = (const float*)d_in[19];
    const float* obn_g  = (const float*)d_in[20];
    const float* obn_b  = (const float*)d_in[21];

    float* ws = (float*)d_ws;
    float* tw = ws;
    float* stats = ws + ST_OFF;
    float* sum1 = stats, *sumsq1 = stats + 64, *sum2 = stats + 128, *sumsq2 = stats + 192;
    unsigned short* M_all = (unsigned short*)(ws + M_OFF);
    unsigned short* vfeat_bf = (unsigned short*)(ws + VF_OFF);
    float* xd = (float*)d_out;    // att -> y -> z -> out, all in place

    prep_all<<<5120, 256, 0, stream>>>(in_w, out_w, lin1_w, lin2_w, outl_w,
                                       vfeat, tw, vfeat_bf, stats);
    m_kernel<<<250, 256, 0, stream>>>(qcoord, q_w, q_b, in_b, tw, M_all);
    attn_kernel<<<N_Q, 64, 0, stream>>>(vfeat_bf, vcoord, qcoord, kidx, kpos_w, kpos_b,
                                        in_b, out_b, tw, M_all, xd);
    ffn_kernel<<<250, 256, 0, stream>>>(tw, lin1_b, lin2_b, xd, sum1, sumsq1);
    linout_kernel<<<250, 256, 0, stream>>>(tw, outl_b, norm_g, norm_b, sum1, sumsq1,
                                           xd, xd, sum2, sumsq2);
    final_kernel<<<1250, 256, 0, stream>>>(xd, sum2, sumsq2, obn_g, obn_b);
}